// Round 5
// baseline (177.250 us; speedup 1.0000x reference)
//
#include <hip/hip_runtime.h>
#include <hip/hip_bf16.h>

typedef unsigned short u16;
typedef unsigned int u32;

#define T_TOK 16384
#define DIM   1024
#define NEXP  8

// ---------- workspace layout (bytes) ----------
// xb      : T*D*2            = 33,554,432
// wb      : E*D*D*2          = 16,777,216
// counts  : 8 ints @64B      = 512
// lists   : E*T*4            = 524,288   (value = tok*2 + k)
// selw    : T*16 (float4)    = 262,144   (e0,e1 bits, w0, w1)
// contrib : T*2*D*2 (bf16)   = 67,108,864
#define XB_OFF      0
#define WB_OFF      33554432
#define CNT_OFF     50331648
#define LIST_OFF    50332160
#define SELW_OFF    50856448
#define CONTRIB_OFF 51380736
#define WS_NEED     118489600ULL

__device__ __forceinline__ u16 f2bf(float f) {
    u32 u = __float_as_uint(f);
    u += 0x7fff + ((u >> 16) & 1);   // round-to-nearest-even
    return (u16)(u >> 16);
}
__device__ __forceinline__ float bf2f(u16 u) {
    return __uint_as_float(((u32)u) << 16);
}

__global__ __launch_bounds__(128) void k_zero(int* counts) {
    if (threadIdx.x < NEXP * 16) counts[threadIdx.x] = 0;
}

// Router + fused expert-weight cvt. Per token: logits (fp32), top-2,
// x->bf16, per-expert lists (tok*2+k), selw={e0,e1,w0,w1}.
#define RT_PB 32

__global__ __launch_bounds__(256) void k_router(
    const float* __restrict__ x, const float* __restrict__ gw,
    const float* __restrict__ gb, float* __restrict__ logits,
    u16* __restrict__ xb, int* __restrict__ counts,
    int* __restrict__ lists, float4* __restrict__ selw,
    const float* __restrict__ ew, u16* __restrict__ wb)
{
    const int tid  = threadIdx.x;
    const int lane = tid & 63;
    const int w    = tid >> 6;

    __shared__ int   s_sel0[RT_PB], s_sel1[RT_PB];
    __shared__ int   s_lcnt[NEXP], s_gbase[NEXP];

    if (tid < NEXP) s_lcnt[tid] = 0;

    for (int i = 0; i < 8; ++i) {
        const int l = w * 8 + i;
        const int t = blockIdx.x * RT_PB + l;

        const float* xr = x + (size_t)t * DIM;
        float4 xs[4];
#pragma unroll
        for (int j = 0; j < 4; ++j)
            xs[j] = *reinterpret_cast<const float4*>(xr + (j * 64 + lane) * 4);

        float acc[NEXP];
#pragma unroll
        for (int e = 0; e < NEXP; ++e) {
            const float* gr = gw + e * DIM;
            float s = 0.f;
#pragma unroll
            for (int j = 0; j < 4; ++j) {
                float4 g = *reinterpret_cast<const float4*>(gr + (j * 64 + lane) * 4);
                s += xs[j].x * g.x + xs[j].y * g.y + xs[j].z * g.z + xs[j].w * g.w;
            }
            acc[e] = s;
        }
#pragma unroll
        for (int off = 1; off < 64; off <<= 1) {
#pragma unroll
            for (int e = 0; e < NEXP; ++e) acc[e] += __shfl_xor(acc[e], off);
        }
#pragma unroll
        for (int e = 0; e < NEXP; ++e) acc[e] += gb[e];

        int i0 = 0; float v0 = acc[0];
#pragma unroll
        for (int e = 1; e < NEXP; ++e) if (acc[e] > v0) { v0 = acc[e]; i0 = e; }
        int i1 = -1; float v1 = -3.4e38f;
#pragma unroll
        for (int e = 0; e < NEXP; ++e) if (e != i0 && acc[e] > v1) { v1 = acc[e]; i1 = e; }
        float e1  = __expf(v1 - v0);
        float inv = 1.f / (1.f + e1);
        float w0 = inv, w1 = e1 * inv;

        u16* xrow = xb + (size_t)t * DIM;
#pragma unroll
        for (int j = 0; j < 4; ++j) {
            int c = (j * 64 + lane) * 4;
            float4 v = xs[j];
            ushort4 u;
            u.x = f2bf(v.x); u.y = f2bf(v.y); u.z = f2bf(v.z); u.w = f2bf(v.w);
            *reinterpret_cast<ushort4*>(xrow + c) = u;
        }
        if (lane == 0) {
            float4 lo = make_float4(acc[0], acc[1], acc[2], acc[3]);
            float4 hi = make_float4(acc[4], acc[5], acc[6], acc[7]);
            *reinterpret_cast<float4*>(logits + (size_t)t * NEXP)     = lo;
            *reinterpret_cast<float4*>(logits + (size_t)t * NEXP + 4) = hi;
            selw[t] = make_float4(__int_as_float(i0), __int_as_float(i1), w0, w1);
            s_sel0[l] = i0; s_sel1[l] = i1;
        }
    }
    __syncthreads();

    int i0 = 0, i1 = 0, r0 = 0, r1 = 0;
    if (tid < RT_PB) {
        i0 = s_sel0[tid]; i1 = s_sel1[tid];
        r0 = atomicAdd(&s_lcnt[i0], 1);
        r1 = atomicAdd(&s_lcnt[i1], 1);
    }
    __syncthreads();
    if (tid < NEXP)
        s_gbase[tid] = atomicAdd(&counts[tid * 16], s_lcnt[tid]);
    __syncthreads();
    if (tid < RT_PB) {
        int t  = blockIdx.x * RT_PB + tid;
        lists[i0 * T_TOK + s_gbase[i0] + r0] = t * 2;
        lists[i1 * T_TOK + s_gbase[i1] + r1] = t * 2 + 1;
    }

    // fused expert-weight f32->bf16 (grid-stride; independent of above)
    const int n4 = NEXP * DIM * DIM / 4;
    const int stride = gridDim.x * 256;
    for (int i = blockIdx.x * 256 + tid; i < n4; i += stride) {
        float4 v = reinterpret_cast<const float4*>(ew)[i];
        ushort4 u;
        u.x = f2bf(v.x); u.y = f2bf(v.y); u.z = f2bf(v.z); u.w = f2bf(v.w);
        reinterpret_cast<ushort4*>(wb)[i] = u;
    }
}

// ======================= grouped GEMM: 128x128, BK=64, 4 waves (2x2),
// 64 KiB LDS dbuf -> 2 blocks/CU. One barrier per phase, counted vmcnt(4)
// (never 0 in main loop), T2 chunk-rotation swizzle, T5 setprio.
//
// Per phase (= one 32-k slice): STAGE 4 gload_lds of next tile's matching
// halves; 8 ds_read_b128; MFMA16; VMW4 (proves the 4 oldest = halves the
// NEXT phase reads); s_barrier. Hazards: ds_reads are consumed by MFMA
// (compiler lgkmcnt) before the closing BAR, so next phase's stores to the
// other half are WAR-safe; RAW on staged data proven by VMW4+BAR.

typedef __attribute__((ext_vector_type(8))) short bf16x8;
typedef __attribute__((ext_vector_type(4))) float f32x4;

#define GLDS16(g, l) __builtin_amdgcn_global_load_lds( \
    (const __attribute__((address_space(1))) void*)(g), \
    (__attribute__((address_space(3))) void*)(l), 16, 0, 0)

#define BAR() __builtin_amdgcn_s_barrier()
#define PRIO1() __builtin_amdgcn_s_setprio(1)
#define PRIO0() __builtin_amdgcn_s_setprio(0)
#define VMW4() asm volatile("s_waitcnt vmcnt(4)" ::: "memory")
#define VMW0() asm volatile("s_waitcnt vmcnt(0)" ::: "memory")

template<int ATOMIC>
__global__ __launch_bounds__(256, 2) void k_gemm(
    const u16* __restrict__ xb, const u16* __restrict__ wb,
    const int* __restrict__ counts, const int* __restrict__ lists,
    const float4* __restrict__ selw, u16* __restrict__ contrib,
    float* __restrict__ out)
{
    __shared__ u16 lds[32768];   // 64 KiB: buf*16384 | A half ks*4096 | B +8192

    const int bid = blockIdx.x;
    const int e   = bid >> 10;          // / (128*8)
    const int mt  = (bid >> 3) & 127;
    const int nt  = bid & 7;
    const int cnt = counts[e * 16];
    if (mt * 128 >= cnt) return;

    const int tid  = threadIdx.x;
    const int lane = tid & 63;
    const int wid  = tid >> 6;
    const int wm   = wid >> 1;
    const int wn   = wid & 1;
    const int listbase = e * T_TOK;

    // staging: round l covers row l*64+(tid>>2), swizzled global chunk
    // cg=((tid&3)-(tid>>3))&3; LDS dest linear = l*2048 + tid*8 (u16).
    const int srow = tid >> 2;
    const int cA   = (((tid & 3) - (tid >> 3)) & 3) * 8;
    int tokA[2];
#pragma unroll
    for (int l = 0; l < 2; ++l) {
        int slot = mt * 128 + l * 64 + srow;
        tokA[l] = lists[listbase + (slot < cnt ? slot : cnt - 1)] >> 1;
    }
    const u16* srcA0 = xb + (size_t)tokA[0] * DIM + cA;
    const u16* srcA1 = xb + (size_t)tokA[1] * DIM + cA;
    const u16* srcB0 = wb + ((size_t)e << 20) + (size_t)(nt * 128 + srow) * DIM + cA;
    const u16* srcB1 = srcB0 + (size_t)64 * DIM;

#define STAGE(nb, ks, kk) do { \
    GLDS16(srcA0 + (kk) + (ks) * 32, &lds[(nb) * 16384 + (ks) * 4096 + wid * 512]); \
    GLDS16(srcA1 + (kk) + (ks) * 32, &lds[(nb) * 16384 + (ks) * 4096 + 2048 + wid * 512]); \
    GLDS16(srcB0 + (kk) + (ks) * 32, &lds[(nb) * 16384 + 8192 + (ks) * 4096 + wid * 512]); \
    GLDS16(srcB1 + (kk) + (ks) * 32, &lds[(nb) * 16384 + 8192 + (ks) * 4096 + 2048 + wid * 512]); } while (0)

    // read: row r, chunk c=lane>>4 stored at cs=(c+(r>>1))&3
    const int cs8  = (((lane >> 4) + ((lane >> 1) & 3)) & 3) * 8;
    const int offA = (wm * 64 + (lane & 15)) * 32 + cs8;
    const int offB = 8192 + (wn * 64 + (lane & 15)) * 32 + cs8;

    bf16x8 Af[4], Bf[4];
    f32x4 acc[4][4];
#pragma unroll
    for (int mi = 0; mi < 4; ++mi)
#pragma unroll
        for (int ni = 0; ni < 4; ++ni) acc[mi][ni] = (f32x4)0.f;

#define LDA4(buf, ks) do { \
    Af[0] = *(const bf16x8*)&lds[(buf) * 16384 + (ks) * 4096 + 0 * 512 + offA]; \
    Af[1] = *(const bf16x8*)&lds[(buf) * 16384 + (ks) * 4096 + 1 * 512 + offA]; \
    Af[2] = *(const bf16x8*)&lds[(buf) * 16384 + (ks) * 4096 + 2 * 512 + offA]; \
    Af[3] = *(const bf16x8*)&lds[(buf) * 16384 + (ks) * 4096 + 3 * 512 + offA]; } while (0)
#define LDB4(buf, ks) do { \
    Bf[0] = *(const bf16x8*)&lds[(buf) * 16384 + (ks) * 4096 + 0 * 512 + offB]; \
    Bf[1] = *(const bf16x8*)&lds[(buf) * 16384 + (ks) * 4096 + 1 * 512 + offB]; \
    Bf[2] = *(const bf16x8*)&lds[(buf) * 16384 + (ks) * 4096 + 2 * 512 + offB]; \
    Bf[3] = *(const bf16x8*)&lds[(buf) * 16384 + (ks) * 4096 + 3 * 512 + offB]; } while (0)
#define MFMA_ROW(i) do { \
    acc[i][0] = __builtin_amdgcn_mfma_f32_16x16x32_bf16(Af[i], Bf[0], acc[i][0], 0, 0, 0); \
    acc[i][1] = __builtin_amdgcn_mfma_f32_16x16x32_bf16(Af[i], Bf[1], acc[i][1], 0, 0, 0); \
    acc[i][2] = __builtin_amdgcn_mfma_f32_16x16x32_bf16(Af[i], Bf[2], acc[i][2], 0, 0, 0); \
    acc[i][3] = __builtin_amdgcn_mfma_f32_16x16x32_bf16(Af[i], Bf[3], acc[i][3], 0, 0, 0); } while (0)
#define MFMA16() do { MFMA_ROW(0); MFMA_ROW(1); MFMA_ROW(2); MFMA_ROW(3); } while (0)

    // prologue: stage K-tile 0; prove its k0 halves (k1 stays in flight)
    STAGE(0, 0, 0); STAGE(0, 1, 0);
    VMW4(); BAR();

    for (int t = 0; t < 15; ++t) {
        const int buf = t & 1, nb = buf ^ 1;
        const int kn  = (t + 1) * 64;
        // ph0: compute ks0, stage next k0
        STAGE(nb, 0, kn);
        LDA4(buf, 0); LDB4(buf, 0);
        PRIO1(); MFMA16(); PRIO0();
        VMW4(); BAR();                 // proves A1,B1(t)
        // ph1: compute ks1, stage next k1
        STAGE(nb, 1, kn);
        LDA4(buf, 1); LDB4(buf, 1);
        PRIO1(); MFMA16(); PRIO0();
        VMW4(); BAR();                 // proves A0,B0(t+1)
    }
    {   // t = 15 (buf 1), no staging
        LDA4(1, 0); LDB4(1, 0);
        PRIO1(); MFMA16(); PRIO0();
        VMW0(); BAR();                 // proves A1,B1(15)
        LDA4(1, 1); LDB4(1, 1);
        PRIO1(); MFMA16(); PRIO0();
    }

    // epilogue: C/D layout col=lane&15, row=(lane>>4)*4+reg
    const int rbase = (lane >> 4) * 4;
    const int cbase = nt * 128 + wn * 64 + (lane & 15);
#pragma unroll
    for (int mi = 0; mi < 4; ++mi) {
#pragma unroll
        for (int r = 0; r < 4; ++r) {
            int slot = mt * 128 + wm * 64 + mi * 16 + rbase + r;
            if (slot < cnt) {
                int lv = lists[listbase + slot];
                if (ATOMIC) {
                    int tok = lv >> 1;
                    float4 sw = selw[tok];
                    float wgt = (lv & 1) ? sw.w : sw.z;
                    float* orow = out + (size_t)tok * DIM + cbase;
#pragma unroll
                    for (int ni = 0; ni < 4; ++ni)
                        atomicAdd(orow + ni * 16, acc[mi][ni][r] * wgt);
                } else {
                    u16* crow = contrib + (size_t)lv * DIM + cbase;
#pragma unroll
                    for (int ni = 0; ni < 4; ++ni)
                        crow[ni * 16] = f2bf(acc[mi][ni][r]);
                }
            }
        }
    }
}

// out[t] = w0*(c0 + b[e0]) + w1*(c1 + b[e1]); 4 tokens/block
__global__ __launch_bounds__(256) void k_combine(
    const u16* __restrict__ contrib, const float4* __restrict__ selw,
    const float* __restrict__ eb, float* __restrict__ out)
{
    const int lane = threadIdx.x & 63;
    const int t    = blockIdx.x * 4 + (threadIdx.x >> 6);
    float4 sw = selw[t];
    const int e0 = __float_as_int(sw.x);
    const int e1 = __float_as_int(sw.y);
    const float w0 = sw.z, w1 = sw.w;
    const u16* c0 = contrib + (size_t)(t * 2) * DIM;
    const u16* c1 = c0 + DIM;
    const float* b0 = eb + e0 * DIM;
    const float* b1 = eb + e1 * DIM;
    float* orow = out + (size_t)t * DIM;
#pragma unroll
    for (int j = 0; j < 2; ++j) {
        const int c = (j * 64 + lane) * 8;
        uint4 u0 = *reinterpret_cast<const uint4*>(c0 + c);
        uint4 u1 = *reinterpret_cast<const uint4*>(c1 + c);
        const u16* p0 = (const u16*)&u0;
        const u16* p1 = (const u16*)&u1;
#pragma unroll
        for (int h = 0; h < 2; ++h) {
            float4 bb0 = *reinterpret_cast<const float4*>(b0 + c + h * 4);
            float4 bb1 = *reinterpret_cast<const float4*>(b1 + c + h * 4);
            float4 o;
            o.x = w0 * (bf2f(p0[h*4+0]) + bb0.x) + w1 * (bf2f(p1[h*4+0]) + bb1.x);
            o.y = w0 * (bf2f(p0[h*4+1]) + bb0.y) + w1 * (bf2f(p1[h*4+1]) + bb1.y);
            o.z = w0 * (bf2f(p0[h*4+2]) + bb0.z) + w1 * (bf2f(p1[h*4+2]) + bb1.z);
            o.w = w0 * (bf2f(p0[h*4+3]) + bb0.w) + w1 * (bf2f(p1[h*4+3]) + bb1.w);
            *reinterpret_cast<float4*>(orow + c + h * 4) = o;
        }
    }
}

// fallback bias-init when ws too small for contrib
__global__ __launch_bounds__(256) void k_bias(
    const float4* __restrict__ selw, const float* __restrict__ eb,
    float* __restrict__ out)
{
    const int lane = threadIdx.x & 63;
    const int t    = blockIdx.x * 4 + (threadIdx.x >> 6);
    float4 sw = selw[t];
    const float* b0 = eb + __float_as_int(sw.x) * DIM;
    const float* b1 = eb + __float_as_int(sw.y) * DIM;
    float* orow = out + (size_t)t * DIM;
#pragma unroll
    for (int j = 0; j < 4; ++j) {
        int c = (j * 64 + lane) * 4;
        float4 f0 = *reinterpret_cast<const float4*>(b0 + c);
        float4 f1 = *reinterpret_cast<const float4*>(b1 + c);
        float4 o;
        o.x = sw.z * f0.x + sw.w * f1.x;
        o.y = sw.z * f0.y + sw.w * f1.y;
        o.z = sw.z * f0.z + sw.w * f1.z;
        o.w = sw.z * f0.w + sw.w * f1.w;
        *reinterpret_cast<float4*>(orow + c) = o;
    }
}

extern "C" void kernel_launch(void* const* d_in, const int* in_sizes, int n_in,
                              void* d_out, int out_size, void* d_ws, size_t ws_size,
                              hipStream_t stream) {
    const float* x  = (const float*)d_in[0];
    const float* gw = (const float*)d_in[1];
    const float* gb = (const float*)d_in[2];
    const float* ew = (const float*)d_in[3];
    const float* eb = (const float*)d_in[4];

    float* out    = (float*)d_out;
    float* logits = out + (size_t)T_TOK * DIM;

    char*   ws      = (char*)d_ws;
    u16*    xb      = (u16*)(ws + XB_OFF);
    u16*    wb      = (u16*)(ws + WB_OFF);
    int*    counts  = (int*)(ws + CNT_OFF);
    int*    lists   = (int*)(ws + LIST_OFF);
    float4* selw    = (float4*)(ws + SELW_OFF);
    u16*    contrib = (u16*)(ws + CONTRIB_OFF);

    k_zero<<<1, 128, 0, stream>>>(counts);
    k_router<<<T_TOK / RT_PB, 256, 0, stream>>>(x, gw, gb, logits, xb, counts,
                                                lists, selw, ew, wb);

    const int grid = NEXP * 128 * 8;   // 128 m-tiles x 8 n-tiles per expert
    if (ws_size >= WS_NEED) {
        k_gemm<0><<<grid, 256, 0, stream>>>(xb, wb, counts, lists, selw, contrib, out);
        k_combine<<<T_TOK / 4, 256, 0, stream>>>(contrib, selw, eb, out);
    } else {
        k_bias<<<T_TOK / 4, 256, 0, stream>>>(selw, eb, out);
        k_gemm<1><<<grid, 256, 0, stream>>>(xb, wb, counts, lists, selw, contrib, out);
    }
}

// Round 6
// 162.442 us; speedup vs baseline: 1.0912x; 1.0912x over previous
//
#include <hip/hip_runtime.h>
#include <hip/hip_bf16.h>

typedef unsigned short u16;
typedef unsigned int u32;

#define T_TOK 16384
#define DIM   1024
#define NEXP  8

// ---------- workspace layout (bytes) ----------
// xb      : T*D*2            = 33,554,432
// wb      : E*D*D*2          = 16,777,216
// counts  : 8 ints @64B      = 512
// lists   : E*T*4            = 524,288   (value = tok*2 + k)
// selw    : T*16 (float4)    = 262,144   (e0,e1 bits, w0, w1)
// contrib : T*2*D*2 (bf16)   = 67,108,864
#define XB_OFF      0
#define WB_OFF      33554432
#define CNT_OFF     50331648
#define LIST_OFF    50332160
#define SELW_OFF    50856448
#define CONTRIB_OFF 51380736
#define WS_NEED     118489600ULL

__device__ __forceinline__ u16 f2bf(float f) {
    u32 u = __float_as_uint(f);
    u += 0x7fff + ((u >> 16) & 1);   // round-to-nearest-even
    return (u16)(u >> 16);
}
__device__ __forceinline__ float bf2f(u16 u) {
    return __uint_as_float(((u32)u) << 16);
}

__global__ __launch_bounds__(128) void k_zero(int* counts) {
    if (threadIdx.x < NEXP * 16) counts[threadIdx.x] = 0;
}

// Router + fused expert-weight cvt. Per token: logits (fp32), top-2,
// x->bf16, per-expert lists (tok*2+k), selw={e0,e1,w0,w1}.
#define RT_PB 32

__global__ __launch_bounds__(256) void k_router(
    const float* __restrict__ x, const float* __restrict__ gw,
    const float* __restrict__ gb, float* __restrict__ logits,
    u16* __restrict__ xb, int* __restrict__ counts,
    int* __restrict__ lists, float4* __restrict__ selw,
    const float* __restrict__ ew, u16* __restrict__ wb)
{
    const int tid  = threadIdx.x;
    const int lane = tid & 63;
    const int w    = tid >> 6;

    __shared__ int   s_sel0[RT_PB], s_sel1[RT_PB];
    __shared__ int   s_lcnt[NEXP], s_gbase[NEXP];

    if (tid < NEXP) s_lcnt[tid] = 0;

    for (int i = 0; i < 8; ++i) {
        const int l = w * 8 + i;
        const int t = blockIdx.x * RT_PB + l;

        const float* xr = x + (size_t)t * DIM;
        float4 xs[4];
#pragma unroll
        for (int j = 0; j < 4; ++j)
            xs[j] = *reinterpret_cast<const float4*>(xr + (j * 64 + lane) * 4);

        float acc[NEXP];
#pragma unroll
        for (int e = 0; e < NEXP; ++e) {
            const float* gr = gw + e * DIM;
            float s = 0.f;
#pragma unroll
            for (int j = 0; j < 4; ++j) {
                float4 g = *reinterpret_cast<const float4*>(gr + (j * 64 + lane) * 4);
                s += xs[j].x * g.x + xs[j].y * g.y + xs[j].z * g.z + xs[j].w * g.w;
            }
            acc[e] = s;
        }
#pragma unroll
        for (int off = 1; off < 64; off <<= 1) {
#pragma unroll
            for (int e = 0; e < NEXP; ++e) acc[e] += __shfl_xor(acc[e], off);
        }
#pragma unroll
        for (int e = 0; e < NEXP; ++e) acc[e] += gb[e];

        int i0 = 0; float v0 = acc[0];
#pragma unroll
        for (int e = 1; e < NEXP; ++e) if (acc[e] > v0) { v0 = acc[e]; i0 = e; }
        int i1 = -1; float v1 = -3.4e38f;
#pragma unroll
        for (int e = 0; e < NEXP; ++e) if (e != i0 && acc[e] > v1) { v1 = acc[e]; i1 = e; }
        float e1  = __expf(v1 - v0);
        float inv = 1.f / (1.f + e1);
        float w0 = inv, w1 = e1 * inv;

        u16* xrow = xb + (size_t)t * DIM;
#pragma unroll
        for (int j = 0; j < 4; ++j) {
            int c = (j * 64 + lane) * 4;
            float4 v = xs[j];
            ushort4 u;
            u.x = f2bf(v.x); u.y = f2bf(v.y); u.z = f2bf(v.z); u.w = f2bf(v.w);
            *reinterpret_cast<ushort4*>(xrow + c) = u;
        }
        if (lane == 0) {
            float4 lo = make_float4(acc[0], acc[1], acc[2], acc[3]);
            float4 hi = make_float4(acc[4], acc[5], acc[6], acc[7]);
            *reinterpret_cast<float4*>(logits + (size_t)t * NEXP)     = lo;
            *reinterpret_cast<float4*>(logits + (size_t)t * NEXP + 4) = hi;
            selw[t] = make_float4(__int_as_float(i0), __int_as_float(i1), w0, w1);
            s_sel0[l] = i0; s_sel1[l] = i1;
        }
    }
    __syncthreads();

    int i0 = 0, i1 = 0, r0 = 0, r1 = 0;
    if (tid < RT_PB) {
        i0 = s_sel0[tid]; i1 = s_sel1[tid];
        r0 = atomicAdd(&s_lcnt[i0], 1);
        r1 = atomicAdd(&s_lcnt[i1], 1);
    }
    __syncthreads();
    if (tid < NEXP)
        s_gbase[tid] = atomicAdd(&counts[tid * 16], s_lcnt[tid]);
    __syncthreads();
    if (tid < RT_PB) {
        int t  = blockIdx.x * RT_PB + tid;
        lists[i0 * T_TOK + s_gbase[i0] + r0] = t * 2;
        lists[i1 * T_TOK + s_gbase[i1] + r1] = t * 2 + 1;
    }

    // fused expert-weight f32->bf16 (grid-stride; independent of above)
    const int n4 = NEXP * DIM * DIM / 4;
    const int stride = gridDim.x * 256;
    for (int i = blockIdx.x * 256 + tid; i < n4; i += stride) {
        float4 v = reinterpret_cast<const float4*>(ew)[i];
        ushort4 u;
        u.x = f2bf(v.x); u.y = f2bf(v.y); u.z = f2bf(v.z); u.w = f2bf(v.w);
        reinterpret_cast<ushort4*>(wb)[i] = u;
    }
}

// ======================= grouped GEMM: 128x128, 4 waves (2x2), K=32 slice
// double-buffer in 32 KiB LDS -> 4 blocks/CU (16 waves/CU, independent
// blocks fill each other's staging stalls). Expert->XCD pinned grid for L2
// weight residency. T2 chunk-rotation swizzle, T5 setprio, depth-1 vmcnt(0).
//
// Per phase: STAGE next 32-k slice (4 gload_lds) into other buffer; 8
// ds_read_b128 of current slice; 16 MFMA; VMW0; BAR. WAR-safe: each wave's
// ds_reads complete before its BAR (compiler lgkmcnt before MFMA uses).

typedef __attribute__((ext_vector_type(8))) short bf16x8;
typedef __attribute__((ext_vector_type(4))) float f32x4;

#define GLDS16(g, l) __builtin_amdgcn_global_load_lds( \
    (const __attribute__((address_space(1))) void*)(g), \
    (__attribute__((address_space(3))) void*)(l), 16, 0, 0)

#define BAR() __builtin_amdgcn_s_barrier()
#define PRIO1() __builtin_amdgcn_s_setprio(1)
#define PRIO0() __builtin_amdgcn_s_setprio(0)
#define VMW0() asm volatile("s_waitcnt vmcnt(0)" ::: "memory")

template<int ATOMIC>
__global__ __launch_bounds__(256, 4) void k_gemm(
    const u16* __restrict__ xb, const u16* __restrict__ wb,
    const int* __restrict__ counts, const int* __restrict__ lists,
    const float4* __restrict__ selw, u16* __restrict__ contrib,
    float* __restrict__ out)
{
    __shared__ u16 lds[16384];   // 32 KiB: buf b*8192 | A [0,4096) | B [4096,8192)

    // expert->XCD pinning: XCD x (= blockIdx%8) owns expert x's 1024 tile slots
    const int bid = (blockIdx.x & 7) * 1024 + (blockIdx.x >> 3);
    const int e   = bid >> 10;
    const int mt  = (bid >> 3) & 127;
    const int nt  = bid & 7;
    const int cnt = counts[e * 16];
    if (mt * 128 >= cnt) return;

    const int tid  = threadIdx.x;
    const int lane = tid & 63;
    const int wid  = tid >> 6;
    const int wm   = wid >> 1;
    const int wn   = wid & 1;
    const int listbase = e * T_TOK;

    // staging: round l covers row l*64+(tid>>2), swizzled global chunk
    // cg=((tid&3)-(tid>>3))&3; LDS dest linear = l*2048 + tid*8 (u16).
    const int srow = tid >> 2;
    const int cA   = (((tid & 3) - (tid >> 3)) & 3) * 8;
    int tokA[2];
#pragma unroll
    for (int l = 0; l < 2; ++l) {
        int slot = mt * 128 + l * 64 + srow;
        tokA[l] = lists[listbase + (slot < cnt ? slot : cnt - 1)] >> 1;
    }
    const u16* srcA0 = xb + (size_t)tokA[0] * DIM + cA;
    const u16* srcA1 = xb + (size_t)tokA[1] * DIM + cA;
    const u16* srcB0 = wb + ((size_t)e << 20) + (size_t)(nt * 128 + srow) * DIM + cA;
    const u16* srcB1 = srcB0 + (size_t)64 * DIM;

#define STAGE(b, kk) do { \
    GLDS16(srcA0 + (kk), &lds[(b) * 8192 + wid * 512]); \
    GLDS16(srcA1 + (kk), &lds[(b) * 8192 + 2048 + wid * 512]); \
    GLDS16(srcB0 + (kk), &lds[(b) * 8192 + 4096 + wid * 512]); \
    GLDS16(srcB1 + (kk), &lds[(b) * 8192 + 4096 + 2048 + wid * 512]); } while (0)

    // read: row r, chunk c=lane>>4 stored at cs=(c+(r>>1))&3
    const int cs8  = (((lane >> 4) + ((lane >> 1) & 3)) & 3) * 8;
    const int offA = (wm * 64 + (lane & 15)) * 32 + cs8;
    const int offB = 4096 + (wn * 64 + (lane & 15)) * 32 + cs8;

    bf16x8 Af[4], Bf[4];
    f32x4 acc[4][4];
#pragma unroll
    for (int mi = 0; mi < 4; ++mi)
#pragma unroll
        for (int ni = 0; ni < 4; ++ni) acc[mi][ni] = (f32x4)0.f;

#define LDA4(b) do { \
    Af[0] = *(const bf16x8*)&lds[(b) * 8192 + 0 * 512 + offA]; \
    Af[1] = *(const bf16x8*)&lds[(b) * 8192 + 1 * 512 + offA]; \
    Af[2] = *(const bf16x8*)&lds[(b) * 8192 + 2 * 512 + offA]; \
    Af[3] = *(const bf16x8*)&lds[(b) * 8192 + 3 * 512 + offA]; } while (0)
#define LDB4(b) do { \
    Bf[0] = *(const bf16x8*)&lds[(b) * 8192 + 0 * 512 + offB]; \
    Bf[1] = *(const bf16x8*)&lds[(b) * 8192 + 1 * 512 + offB]; \
    Bf[2] = *(const bf16x8*)&lds[(b) * 8192 + 2 * 512 + offB]; \
    Bf[3] = *(const bf16x8*)&lds[(b) * 8192 + 3 * 512 + offB]; } while (0)
#define MFMA_ROW(i) do { \
    acc[i][0] = __builtin_amdgcn_mfma_f32_16x16x32_bf16(Af[i], Bf[0], acc[i][0], 0, 0, 0); \
    acc[i][1] = __builtin_amdgcn_mfma_f32_16x16x32_bf16(Af[i], Bf[1], acc[i][1], 0, 0, 0); \
    acc[i][2] = __builtin_amdgcn_mfma_f32_16x16x32_bf16(Af[i], Bf[2], acc[i][2], 0, 0, 0); \
    acc[i][3] = __builtin_amdgcn_mfma_f32_16x16x32_bf16(Af[i], Bf[3], acc[i][3], 0, 0, 0); } while (0)
#define MFMA16() do { MFMA_ROW(0); MFMA_ROW(1); MFMA_ROW(2); MFMA_ROW(3); } while (0)

    // prologue: stage slice 0
    STAGE(0, 0);
    VMW0(); BAR();

    for (int s = 0; s < 31; ++s) {
        const int b = s & 1, nb = b ^ 1;
        STAGE(nb, (s + 1) * 32);
        LDA4(b); LDB4(b);
        PRIO1(); MFMA16(); PRIO0();
        VMW0(); BAR();                 // slice s+1 proven for next phase
    }
    {   // s = 31 (buf 1), no staging
        LDA4(1); LDB4(1);
        PRIO1(); MFMA16(); PRIO0();
    }

    // epilogue: C/D layout col=lane&15, row=(lane>>4)*4+reg
    const int rbase = (lane >> 4) * 4;
    const int cbase = nt * 128 + wn * 64 + (lane & 15);
#pragma unroll
    for (int mi = 0; mi < 4; ++mi) {
#pragma unroll
        for (int r = 0; r < 4; ++r) {
            int slot = mt * 128 + wm * 64 + mi * 16 + rbase + r;
            if (slot < cnt) {
                int lv = lists[listbase + slot];
                if (ATOMIC) {
                    int tok = lv >> 1;
                    float4 sw = selw[tok];
                    float wgt = (lv & 1) ? sw.w : sw.z;
                    float* orow = out + (size_t)tok * DIM + cbase;
#pragma unroll
                    for (int ni = 0; ni < 4; ++ni)
                        atomicAdd(orow + ni * 16, acc[mi][ni][r] * wgt);
                } else {
                    u16* crow = contrib + (size_t)lv * DIM + cbase;
#pragma unroll
                    for (int ni = 0; ni < 4; ++ni)
                        crow[ni * 16] = f2bf(acc[mi][ni][r]);
                }
            }
        }
    }
}

// out[t] = w0*(c0 + b[e0]) + w1*(c1 + b[e1]); 4 tokens/block
__global__ __launch_bounds__(256) void k_combine(
    const u16* __restrict__ contrib, const float4* __restrict__ selw,
    const float* __restrict__ eb, float* __restrict__ out)
{
    const int lane = threadIdx.x & 63;
    const int t    = blockIdx.x * 4 + (threadIdx.x >> 6);
    float4 sw = selw[t];
    const int e0 = __float_as_int(sw.x);
    const int e1 = __float_as_int(sw.y);
    const float w0 = sw.z, w1 = sw.w;
    const u16* c0 = contrib + (size_t)(t * 2) * DIM;
    const u16* c1 = c0 + DIM;
    const float* b0 = eb + e0 * DIM;
    const float* b1 = eb + e1 * DIM;
    float* orow = out + (size_t)t * DIM;
#pragma unroll
    for (int j = 0; j < 2; ++j) {
        const int c = (j * 64 + lane) * 8;
        uint4 u0 = *reinterpret_cast<const uint4*>(c0 + c);
        uint4 u1 = *reinterpret_cast<const uint4*>(c1 + c);
        const u16* p0 = (const u16*)&u0;
        const u16* p1 = (const u16*)&u1;
#pragma unroll
        for (int h = 0; h < 2; ++h) {
            float4 bb0 = *reinterpret_cast<const float4*>(b0 + c + h * 4);
            float4 bb1 = *reinterpret_cast<const float4*>(b1 + c + h * 4);
            float4 o;
            o.x = w0 * (bf2f(p0[h*4+0]) + bb0.x) + w1 * (bf2f(p1[h*4+0]) + bb1.x);
            o.y = w0 * (bf2f(p0[h*4+1]) + bb0.y) + w1 * (bf2f(p1[h*4+1]) + bb1.y);
            o.z = w0 * (bf2f(p0[h*4+2]) + bb0.z) + w1 * (bf2f(p1[h*4+2]) + bb1.z);
            o.w = w0 * (bf2f(p0[h*4+3]) + bb0.w) + w1 * (bf2f(p1[h*4+3]) + bb1.w);
            *reinterpret_cast<float4*>(orow + c + h * 4) = o;
        }
    }
}

// fallback bias-init when ws too small for contrib
__global__ __launch_bounds__(256) void k_bias(
    const float4* __restrict__ selw, const float* __restrict__ eb,
    float* __restrict__ out)
{
    const int lane = threadIdx.x & 63;
    const int t    = blockIdx.x * 4 + (threadIdx.x >> 6);
    float4 sw = selw[t];
    const float* b0 = eb + __float_as_int(sw.x) * DIM;
    const float* b1 = eb + __float_as_int(sw.y) * DIM;
    float* orow = out + (size_t)t * DIM;
#pragma unroll
    for (int j = 0; j < 4; ++j) {
        int c = (j * 64 + lane) * 4;
        float4 f0 = *reinterpret_cast<const float4*>(b0 + c);
        float4 f1 = *reinterpret_cast<const float4*>(b1 + c);
        float4 o;
        o.x = sw.z * f0.x + sw.w * f1.x;
        o.y = sw.z * f0.y + sw.w * f1.y;
        o.z = sw.z * f0.z + sw.w * f1.z;
        o.w = sw.z * f0.w + sw.w * f1.w;
        *reinterpret_cast<float4*>(orow + c) = o;
    }
}

extern "C" void kernel_launch(void* const* d_in, const int* in_sizes, int n_in,
                              void* d_out, int out_size, void* d_ws, size_t ws_size,
                              hipStream_t stream) {
    const float* x  = (const float*)d_in[0];
    const float* gw = (const float*)d_in[1];
    const float* gb = (const float*)d_in[2];
    const float* ew = (const float*)d_in[3];
    const float* eb = (const float*)d_in[4];

    float* out    = (float*)d_out;
    float* logits = out + (size_t)T_TOK * DIM;

    char*   ws      = (char*)d_ws;
    u16*    xb      = (u16*)(ws + XB_OFF);
    u16*    wb      = (u16*)(ws + WB_OFF);
    int*    counts  = (int*)(ws + CNT_OFF);
    int*    lists   = (int*)(ws + LIST_OFF);
    float4* selw    = (float4*)(ws + SELW_OFF);
    u16*    contrib = (u16*)(ws + CONTRIB_OFF);

    k_zero<<<1, 128, 0, stream>>>(counts);
    k_router<<<T_TOK / RT_PB, 256, 0, stream>>>(x, gw, gb, logits, xb, counts,
                                                lists, selw, ew, wb);

    const int grid = NEXP * 128 * 8;   // expert-pinned: XCD x gets expert x
    if (ws_size >= WS_NEED) {
        k_gemm<0><<<grid, 256, 0, stream>>>(xb, wb, counts, lists, selw, contrib, out);
        k_combine<<<T_TOK / 4, 256, 0, stream>>>(contrib, selw, eb, out);
    } else {
        k_bias<<<T_TOK / 4, 256, 0, stream>>>(selw, eb, out);
        k_gemm<1><<<grid, 256, 0, stream>>>(xb, wb, counts, lists, selw, contrib, out);
    }
}